// Round 16
// baseline (4644.526 us; speedup 1.0000x reference)
//
#include <hip/hip_runtime.h>
#include <hip/hip_bf16.h>
#include <math.h>

typedef unsigned short u16;
typedef unsigned int   u32;
typedef unsigned long long u64;
typedef __attribute__((ext_vector_type(8))) short short8;
typedef __attribute__((ext_vector_type(4))) float float4v;

#define BB 64
#define SS 512

// bf16 helpers (RNE)
__device__ __forceinline__ u16 f2b(float f) {
    u32 x = __float_as_uint(f);
    u32 r = (x + 0x7fffu + ((x >> 16) & 1u)) >> 16;
    return (u16)r;
}
__device__ __forceinline__ float b2f(u32 lo16) { return __uint_as_float(lo16 << 16); }
__device__ __forceinline__ float b2fh(u32 v)   { return __uint_as_float(v & 0xffff0000u); }

// ---------------------------------------------------------------------------
__global__ __launch_bounds__(256) void zero_kernel(float* __restrict__ p, int n) {
    int i = blockIdx.x * 256 + threadIdx.x;
    if (i < n) p[i] = 0.f;
}

// ---------------------------------------------------------------------------
__global__ __launch_bounds__(256) void pe_kernel(float* __restrict__ pe) {
    int s = blockIdx.x, j = threadIdx.x;
    float ang = (float)s * powf(10000.0f, -(2.0f * (float)j) / 512.0f);
    pe[s * 512 + 2 * j]     = sinf(ang);
    pe[s * 512 + 2 * j + 1] = cosf(ang);
}

// ---------------------------------------------------------------------------
// Merged setup transpose: z=0 Wcomb [1024][512]->[512][1024];
// z=1..3 Wq/Wk/Wv [512][512]->[512][512]. Body identical to the validated
// transp_w (C=512 always; R varies). Uniform early-return for z>0, bx>=8.
// ---------------------------------------------------------------------------
__global__ __launch_bounds__(256) void transp_w4(
    const float* __restrict__ i0, u16* __restrict__ o0,
    const float* __restrict__ i1, u16* __restrict__ o1,
    const float* __restrict__ i2, u16* __restrict__ o2,
    const float* __restrict__ i3, u16* __restrict__ o3)
{
    __shared__ float t[64][65];
    int z = blockIdx.z;
    const float* in; u16* out; int R;
    if (z == 0) { in = i0; out = o0; R = 1024; }
    else {
        if (blockIdx.x >= 8) return;        // uniform for the whole block
        R = 512;
        if (z == 1)      { in = i1; out = o1; }
        else if (z == 2) { in = i2; out = o2; }
        else             { in = i3; out = o3; }
    }
    int r0 = blockIdx.x * 64, c0 = blockIdx.y * 64;
    int tid = threadIdx.x;
    int lr = tid >> 4, lc4 = (tid & 15) * 4;
#pragma unroll
    for (int i = 0; i < 4; i++) {
        int r = lr + i * 16;
        float4 v = *(const float4*)(in + (long)(r0 + r) * 512 + c0 + lc4);
        t[r][lc4] = v.x; t[r][lc4 + 1] = v.y; t[r][lc4 + 2] = v.z; t[r][lc4 + 3] = v.w;
    }
    __syncthreads();
#pragma unroll
    for (int i = 0; i < 4; i++) {
        int c = lr + i * 16;
        u32 lo = (u32)f2b(t[lc4][c])     | ((u32)f2b(t[lc4 + 1][c]) << 16);
        u32 hi = (u32)f2b(t[lc4 + 2][c]) | ((u32)f2b(t[lc4 + 3][c]) << 16);
        uint2 pk; pk.x = lo; pk.y = hi;
        *(uint2*)(out + (long)(c0 + c) * R + r0 + lc4) = pk;
    }
}

// ---------------------------------------------------------------------------
// Merged dual bf16 convert (Wi and Wh, same length)
// ---------------------------------------------------------------------------
__global__ __launch_bounds__(256) void cvt_bf16_2(
    const float* __restrict__ in0, u16* __restrict__ out0,
    const float* __restrict__ in1, u16* __restrict__ out1, long n)
{
    long i = (long)blockIdx.x * 256 + threadIdx.x;
    if (i < n) {
        out0[i] = f2b(in0[i]);
        out1[i] = f2b(in1[i]);
    }
}

// ---------------------------------------------------------------------------
// bf16 [nb][R][C(ldin)] -> out[b][c][r] with element strides
// ---------------------------------------------------------------------------
__global__ __launch_bounds__(256) void transp_b(const u16* __restrict__ in,
                                                u16* __restrict__ out,
                                                int R, int C, int ldin,
                                                long sbin, long sb, long sc) {
    __shared__ u32 t[64][65];
    int bz = blockIdx.z;
    in += (long)bz * sbin;
    int r0 = blockIdx.x * 64, c0 = blockIdx.y * 64;
    int tid = threadIdx.x;
    int lr = tid >> 4, lc4 = (tid & 15) * 4;
#pragma unroll
    for (int i = 0; i < 4; i++) {
        int r = lr + i * 16;
        uint2 v = *(const uint2*)(in + (long)(r0 + r) * ldin + c0 + lc4);
        t[r][lc4] = v.x & 0xffffu; t[r][lc4 + 1] = v.x >> 16;
        t[r][lc4 + 2] = v.y & 0xffffu; t[r][lc4 + 3] = v.y >> 16;
    }
    __syncthreads();
#pragma unroll
    for (int i = 0; i < 4; i++) {
        int c = lr + i * 16;
        uint2 pk;
        pk.x = t[lc4][c] | (t[lc4 + 1][c] << 16);
        pk.y = t[lc4 + 2][c] | (t[lc4 + 3][c] << 16);
        *(uint2*)(out + (long)bz * sb + (long)(c0 + c) * sc + r0 + lc4) = pk;
    }
}

// ---------------------------------------------------------------------------
__global__ __launch_bounds__(256) void embed_kernel(
    const int* __restrict__ cate, const float* __restrict__ cont,
    const float* __restrict__ emb, const float* __restrict__ Wc,
    const float* __restrict__ bc, u16* __restrict__ xc, int gbase)
{
    long bs = (long)gbase + blockIdx.x;
    long r  = blockIdx.x;
    __shared__ float cf[6];
    if (threadIdx.x < 6) cf[threadIdx.x] = cont[bs * 6 + threadIdx.x];
    __syncthreads();
    for (int h = threadIdx.x; h < 1024; h += 256) {
        float v;
        if (h < 512) {
            int c = h >> 7, e = h & 127;
            int idx = cate[bs * 4 + c];
            v = emb[((long)c * 1000 + idx) * 128 + e];
        } else {
            int hh = h - 512;
            v = bc[hh];
#pragma unroll
            for (int f = 0; f < 6; f++) v += cf[f] * Wc[f * 512 + hh];
        }
        xc[r * 1024 + h] = f2b(v);
    }
}

// ---------------------------------------------------------------------------
// bf16 MFMA NT GEMM (validated: absmax 0.0)
// ---------------------------------------------------------------------------
__global__ __launch_bounds__(256) void gemm_nt(
    const u16* __restrict__ A, const u16* __restrict__ B, void* __restrict__ Cv,
    int K, int lda, int ldb, int ldc,
    long sA, long sB, long sC,
    const float* __restrict__ bias, const float* __restrict__ pe,
    float alpha, int outBf16)
{
    __shared__ u16 As[128][40];
    __shared__ u16 Bs[128][40];

    A += (long)blockIdx.z * sA;
    B += (long)blockIdx.z * sB;
    int m0 = blockIdx.y * 128, n0 = blockIdx.x * 128;
    int tid = threadIdx.x;
    int lane = tid & 63, wid = tid >> 6;
    int wm = (wid >> 1) * 64, wn = (wid & 1) * 64;
    int mrow = lane & 15, q8 = (lane >> 4) * 8;

    float4v acc[4][4];
#pragma unroll
    for (int i = 0; i < 4; i++)
#pragma unroll
        for (int j = 0; j < 4; j++) { float4v z = {0.f, 0.f, 0.f, 0.f}; acc[i][j] = z; }

    for (int k0 = 0; k0 < K; k0 += 32) {
        {
            int r = tid >> 2, sg = tid & 3;
            *(short8*)&As[r][sg * 8] = *(const short8*)(A + (long)(m0 + r) * lda + k0 + sg * 8);
            *(short8*)&Bs[r][sg * 8] = *(const short8*)(B + (long)(n0 + r) * ldb + k0 + sg * 8);
            r = (tid + 256) >> 2;
            *(short8*)&As[r][sg * 8] = *(const short8*)(A + (long)(m0 + r) * lda + k0 + sg * 8);
            *(short8*)&Bs[r][sg * 8] = *(const short8*)(B + (long)(n0 + r) * ldb + k0 + sg * 8);
        }
        __syncthreads();
        short8 af[4], bfr[4];
#pragma unroll
        for (int t = 0; t < 4; t++) {
            af[t]  = *(const short8*)&As[wm + t * 16 + mrow][q8];
            bfr[t] = *(const short8*)&Bs[wn + t * 16 + mrow][q8];
        }
#pragma unroll
        for (int i = 0; i < 4; i++)
#pragma unroll
            for (int j = 0; j < 4; j++)
                acc[i][j] = __builtin_amdgcn_mfma_f32_16x16x32_bf16(af[i], bfr[j], acc[i][j], 0, 0, 0);
        __syncthreads();
    }

    int col = lane & 15, quad = lane >> 4;
    u16*  Cb = (u16*)Cv  + (outBf16 ? (long)blockIdx.z * sC : 0);
    float* Cf = (float*)Cv + (outBf16 ? 0 : (long)blockIdx.z * sC);
#pragma unroll
    for (int i = 0; i < 4; i++)
#pragma unroll
        for (int j = 0; j < 4; j++) {
#pragma unroll
            for (int rr = 0; rr < 4; rr++) {
                int gm = m0 + wm + i * 16 + quad * 4 + rr;
                int gn = n0 + wn + j * 16 + col;
                float v = acc[i][j][rr] * alpha;
                if (bias) v += bias[gn];
                if (pe)   v += pe[(long)(gm & 511) * 512 + gn];
                if (outBf16) Cb[(long)gm * ldc + gn] = f2b(v);
                else         Cf[(long)gm * ldc + gn] = v;
            }
        }
}

// ---------------------------------------------------------------------------
// Softmax over QUERY axis fp32 -> bf16
// ---------------------------------------------------------------------------
__global__ __launch_bounds__(64) void softmax_q(const float* __restrict__ S,
                                                u16* __restrict__ P) {
    int b = blockIdx.x;
    int k = blockIdx.y * 64 + threadIdx.x;
    const float* p = S + (long)b * 262144 + k;
    u16* o = P + (long)b * 262144 + k;
    float m = -1e30f;
    for (int q = 0; q < 512; q++) m = fmaxf(m, p[(long)q * 512]);
    float sum = 0.f;
    for (int q = 0; q < 512; q++) sum += expf(p[(long)q * 512] - m);
    float inv = 1.f / sum;
    for (int q = 0; q < 512; q++) o[(long)q * 512] = f2b(expf(p[(long)q * 512] - m) * inv);
}

// ---------------------------------------------------------------------------
// R16 GRU = R8/R13 VERBATIM (validated absmax 0.0, 392 us/dispatch).
// 128 blocks = 8 XCD-confined batch-groups(8 batches) x 16 unit-slices(32
// units); recurrent matvec = MFMA M=8 x N=96 x K=512 with Wh B-fragments
// preloaded ONCE into registers; h exchange = relaxed tag+spin u64 ring,
// batched 8-load sweeps, parity double buffer, 2-barrier loop.
// In-kernel input-gate fusion PERMANENTLY CLOSED after three consistent
// 1.56e-2 failures (R12/R14/R15) that resisted localization; the gi GEMM
// path stays (validated bit-reproducible).
// hx: u64[2 parity][8 bg][2048 slot], slot = pr*8 + b.
// ---------------------------------------------------------------------------
__global__ __launch_bounds__(256, 1) void gru_mfma(
    const float* __restrict__ gi,     // [128][64][1536] fp32 (includes bi)
    const u16*  __restrict__ WhB,     // [1536][512] bf16 (this layer)
    const float* __restrict__ bh_l,   // [1536]
    u16* __restrict__ seq_out,        // [512*64][512] bf16 (this layer)
    u64* __restrict__ hx,             // [2][8][2048] u64
    int s0, int layer)
{
    __shared__ u16 hlds[16 * 512];    // 16384 B  A-matrix h[b][k] bf16 (rows 8-15 zero)
    __shared__ float pre[3 * 16 * 34];// 6528 B   pre-activations [gate][b][u] (pad 34)
    __shared__ float hprev[8 * 32];   // 1024 B   own slice h fp32

    int blk = blockIdx.x;
    int bg  = blk & 7;                // batch group (8 batches) == XCD (round-robin)
    int us  = blk >> 3;               // unit slice 0..15 (32 units)
    int tid = threadIdx.x;
    int lane = tid & 63, wid = tid >> 6;

    // finalize mapping: thread (tid<128) = (batch fb 0..7, unit-pair up 0..15)
    int fb = (tid >> 4) & 7, up = tid & 15;
    int u0 = up << 1;
    int ug = (us << 5) + u0;          // global unit of u0
    float2 bhr = *(const float2*)(bh_l + ug);
    float2 bhz = *(const float2*)(bh_l + 512 + ug);
    float2 bhn = *(const float2*)(bh_l + 1024 + ug);

    // MFMA wave assignment: wid 0:{t0,t1} 1:{t2,t3} 2:{t4} 3:{t5}
    int t0 = (wid < 2) ? (wid << 1) : (wid + 2);
    int nt2 = (wid < 2);
    int bq = lane & 15, kq = (lane >> 4) << 3;
    char* hbase = (char*)hlds + (bq << 10);
    int swz = (bq & 7) << 4;

    // ---- preload B fragments into registers (constant across all steps).
    short8 br0[16], br1[16];
    {
        int r_0 = (t0 << 4) + bq;
        long grow0 = (long)((r_0 >> 5) << 9) + (us << 5) + (r_0 & 31);
        const u16* wp0 = WhB + grow0 * 512 + kq;
#pragma unroll
        for (int ks = 0; ks < 16; ks++) br0[ks] = *(const short8*)(wp0 + ks * 32);
        if (nt2) {
            int r_1 = r_0 + 16;
            long grow1 = (long)((r_1 >> 5) << 9) + (us << 5) + (r_1 & 31);
            const u16* wp1 = WhB + grow1 * 512 + kq;
#pragma unroll
            for (int ks = 0; ks < 16; ks++) br1[ks] = *(const short8*)(wp1 + ks * 32);
        } else {
#pragma unroll
            for (int ks = 0; ks < 16; ks++) br1[ks] = br0[ks];
        }
    }

    for (int sl = 0; sl < 128; sl++) {
        int s = s0 + sl;

        // ---- gi prefetch (waves 0-1 only; independent of h exchange) ----
        float2 gir = {0.f, 0.f}, giz = {0.f, 0.f}, gin = {0.f, 0.f};
        if (tid < 128) {
            const float* g = gi + ((long)sl * 64 + (bg << 3) + fb) * 1536 + ug;
            gir = *(const float2*)g;
            giz = *(const float2*)(g + 512);
            gin = *(const float2*)(g + 1024);
        }

        // ---- gather h (or zero-init at layer start) ----
        if (s == 0) {
            u32* hz = (u32*)hlds;
            for (int i = tid; i < 4096; i += 256) hz[i] = 0;
        } else {
            u32 exp_tag = (u32)(layer * 512 + s);
            const u64* src = hx + ((long)(exp_tag & 1) << 14) + ((long)bg << 11) + tid;
            u32 need = 0xffu;
            int guard = 0;
            while (need) {
                // batch-issue all 8 loads (same-XCD L2 hits: cheap sweeps)
                u64 v[8];
#pragma unroll
                for (int j = 0; j < 8; j++)
                    v[j] = __hip_atomic_load(src + (j << 8), __ATOMIC_RELAXED, __HIP_MEMORY_SCOPE_AGENT);
#pragma unroll
                for (int j = 0; j < 8; j++) {
                    if ((need & (1u << j)) && (u32)(v[j] >> 32) == exp_tag) {
                        int i = tid + (j << 8);
                        int b = i & 7, pr = i >> 3;
                        *(u32*)((char*)hlds + ((b << 10) + ((pr << 2) ^ (b << 4)))) = (u32)v[j];
                        need &= ~(1u << j);
                    }
                }
                if (need) {
                    __builtin_amdgcn_s_sleep(1);
                    if (++guard > (1 << 12)) break;   // safety: never fires in correct runs
                }
            }
        }
        __syncthreads();   // barrier A: hlds complete

        // ---- segment start: restore own-slice fp32 h from gathered bf16 ----
        if (sl == 0 && tid < 128) {
            int pr = (us << 4) + up;
            u32 pk = *(u32*)((char*)hlds + ((fb << 10) + ((pr << 2) ^ (fb << 4))));
            hprev[(fb << 5) + u0]     = b2f(pk & 0xffffu);
            hprev[(fb << 5) + u0 + 1] = b2fh(pk);
        }

        // ---- MFMA: pre[16 b][96 gcol] = h[16][512] @ W[96][512]^T
        //      (B from registers; only 16 A ds_reads per wave) ----
        {
            float4v acc0 = {0.f, 0.f, 0.f, 0.f}, acc1 = {0.f, 0.f, 0.f, 0.f};
#pragma unroll
            for (int ks = 0; ks < 16; ks++) {
                int k2 = ((ks << 5) + kq) << 1;           // byte offset of k
                short8 a = *(const short8*)(hbase + (k2 ^ swz));
                acc0 = __builtin_amdgcn_mfma_f32_16x16x32_bf16(a, br0[ks], acc0, 0, 0, 0);
                if (nt2)
                    acc1 = __builtin_amdgcn_mfma_f32_16x16x32_bf16(a, br1[ks], acc1, 0, 0, 0);
            }
            int gq = lane >> 4;
            int g0 = t0 >> 1;
            int uu0 = ((t0 << 4) + (lane & 15)) & 31;
#pragma unroll
            for (int rr = 0; rr < 4; rr++) {
                int b = (gq << 2) + rr;
                pre[(g0 * 16 + b) * 34 + uu0] = acc0[rr];
                if (nt2) {
                    int t1 = t0 + 1;
                    int uu1 = ((t1 << 4) + (lane & 15)) & 31;
                    pre[((t1 >> 1) * 16 + b) * 34 + uu1] = acc1[rr];
                }
            }
        }
        __syncthreads();   // barrier B: pre complete; hlds reads done

        // ---- finalize: waves 0-1, 128 threads x 2 units (no barrier
        //      after; store drains overlap the next gather's spin) ----
        if (tid < 128) {
            float2 sr = *(const float2*)&pre[(0 * 16 + fb) * 34 + u0];
            float2 sz = *(const float2*)&pre[(1 * 16 + fb) * 34 + u0];
            float2 sn = *(const float2*)&pre[(2 * 16 + fb) * 34 + u0];
            float r0v = 1.f / (1.f + expf(-(gir.x + sr.x + bhr.x)));
            float r1v = 1.f / (1.f + expf(-(gir.y + sr.y + bhr.y)));
            float z0v = 1.f / (1.f + expf(-(giz.x + sz.x + bhz.x)));
            float z1v = 1.f / (1.f + expf(-(giz.y + sz.y + bhz.y)));
            float n0v = tanhf(gin.x + r0v * (sn.x + bhn.x));
            float n1v = tanhf(gin.y + r1v * (sn.y + bhn.y));
            float hp0 = hprev[(fb << 5) + u0];
            float hp1 = hprev[(fb << 5) + u0 + 1];
            float hn0 = (1.f - z0v) * n0v + z0v * hp0;
            float hn1 = (1.f - z1v) * n1v + z1v * hp1;
            hprev[(fb << 5) + u0]     = hn0;
            hprev[(fb << 5) + u0 + 1] = hn1;
            u16 q0 = f2b(hn0), q1 = f2b(hn1);
            u32 pk = ((u32)q1 << 16) | (u32)q0;
            u32 wt = (u32)(layer * 512 + s + 1);
            u64 pv = ((u64)wt << 32) | (u64)pk;
            int slot = (((us << 4) + up) << 3) + fb;   // pr*8 + b
            u64* dst = hx + ((long)(wt & 1) << 14) + ((long)bg << 11) + slot;
            __hip_atomic_store(dst, pv, __ATOMIC_RELAXED, __HIP_MEMORY_SCOPE_AGENT);
            *(u32*)(seq_out + ((long)s * 64 + (bg << 3) + fb) * 512 + ug) = pk;
        }
        // no barrier: finalize(t) ∥ gather(t+1) touch disjoint LDS
    }
}

// ---------------------------------------------------------------------------
__global__ __launch_bounds__(256) void final_kernel(
    const u16* __restrict__ h2, const float* __restrict__ Wf,
    const float* __restrict__ bfin, float* __restrict__ out)
{
    int w = blockIdx.x * 4 + (threadIdx.x >> 6);
    int lane = threadIdx.x & 63;
    const u16* row = h2 + (long)w * 512;
    uint4 hv = *(const uint4*)(row + lane * 8);
    float4 w0 = *(const float4*)(Wf + lane * 8);
    float4 w1 = *(const float4*)(Wf + lane * 8 + 4);
    float sum = b2f(hv.x & 0xffffu) * w0.x + b2fh(hv.x) * w0.y
              + b2f(hv.y & 0xffffu) * w0.z + b2fh(hv.y) * w0.w
              + b2f(hv.z & 0xffffu) * w1.x + b2fh(hv.z) * w1.y
              + b2f(hv.w & 0xffffu) * w1.z + b2fh(hv.w) * w1.w;
#pragma unroll
    for (int off = 32; off > 0; off >>= 1) sum += __shfl_down(sum, off, 64);
    if (lane == 0) {
        int s = w >> 6, b = w & 63;
        out[(long)b * 512 + s] = 1.f / (1.f + expf(-(sum + bfin[0])));
    }
}

// ---------------------------------------------------------------------------
// Launcher — workspace ~169.4 MB. R16 = R13 + merged setup launches
// (transp_w x4 -> transp_w4 x1; cvt_bf16 x2 -> cvt_bf16_2 x1). Phase-1
// (R11) and phase-2 (R13) consolidations and the R8-verbatim GRU kept.
// ---------------------------------------------------------------------------
extern "C" void kernel_launch(void* const* d_in, const int* in_sizes, int n_in,
                              void* d_out, int out_size, void* d_ws, size_t ws_size,
                              hipStream_t stream) {
    const int*   cate  = (const int*)  d_in[0];
    const float* cont  = (const float*)d_in[1];
    const float* emb   = (const float*)d_in[4];
    const float* Wc    = (const float*)d_in[5];
    const float* bc    = (const float*)d_in[6];
    const float* Wcomb = (const float*)d_in[7];
    const float* bcomb = (const float*)d_in[8];
    const float* Wq    = (const float*)d_in[9];
    const float* Wk    = (const float*)d_in[10];
    const float* Wv    = (const float*)d_in[11];
    const float* Wi    = (const float*)d_in[12];
    const float* Wh    = (const float*)d_in[13];
    const float* bi    = (const float*)d_in[14];
    const float* bh    = (const float*)d_in[15];
    const float* Wf    = (const float*)d_in[16];
    const float* bfin  = (const float*)d_in[17];
    float* out = (float*)d_out;
    char* ws = (char*)d_ws;

    u16*   xcF   = (u16*)(ws + 0);            // phase-1 only: [32768][1024] = 67 MB
    u16*   zp    = (u16*)(ws + 0);            // phase-2 out / phase-3 L0 in
    u16*   h2bf  = (u16*)(ws + 0);            // phase-3 L1 out (zp dead by then)
    u16*   h1bf  = (u16*)(ws + 33554432);     // phase-3 only
    u16*   Pg2   = (u16*)(ws + 33554432);     // phase-2 only (h1bf region)
    u16*   zT2   = (u16*)(ws + 41943040);     // phase-2 only (h1bf region)
    float* gi    = (float*)(ws + 67108864);   // phase-3, 50.3 MB (overlaps xbf+QKV2)
    u16*   xbf   = (u16*)(ws + 67108864);     // 33.5 MB
    u16*   QKV2  = (u16*)(ws + 100663296);    // phase-2: [8192][1536] bf16 = 25.2 MB
    float* Sg2   = (float*)(ws + 125829120);  // phase-2: [16][512][512] fp32 = 16.8 MB
    u64*   hx    = (u64*)  (ws + 134217728);  // phase-3: 256 KB (inside dead Sg2)
    u16*   Vt2   = (u16*)(ws + 142606336);    // phase-2: 8.4 MB
    u16*   WcombT= (u16*)(ws + 159383552);
    u16*   WqT   = (u16*)(ws + 160432128);    // contiguous: WqT|WkT|WvT = [1536][512]
    u16*   WkT   = (u16*)(ws + 160956416);
    u16*   WvT   = (u16*)(ws + 161480704);
    u16*   WiB   = (u16*)(ws + 162004992);
    float* pe    = (float*)(ws + 165150720);
    u16*   WhB   = (u16*)(ws + 166199296);    // [2][1536][512] bf16 = 3.15 MB

    transp_w4<<<dim3(16, 8, 4), 256, 0, stream>>>(Wcomb, WcombT, Wq, WqT,
                                                  Wk, WkT, Wv, WvT);
    cvt_bf16_2<<<6144, 256, 0, stream>>>(Wi, WiB, Wh, WhB, 2L * 1536 * 512);
    pe_kernel<<<512, 256, 0, stream>>>(pe);

    // phase 1 — consolidated: ONE embed + ONE GEMM (R11)
    embed_kernel<<<32768, 256, 0, stream>>>(cate, cont, emb, Wc, bc, xcF, 0);
    gemm_nt<<<dim3(4, 256, 1), 256, 0, stream>>>(
        xcF, WcombT, xbf, 1024, 1024, 1024, 512,
        0, 0, 0, bcomb, pe, 1.f, 1);

    // phase 2 — 4 super-groups of 16 batches (6 launches each) (R13)
    for (int G = 0; G < 4; G++) {
        const u16* xg = xbf + (long)G * 16 * 512 * 512;
        gemm_nt<<<dim3(12, 64, 1), 256, 0, stream>>>(xg, WqT, QKV2, 512,
                                                     512, 512, 1536,
                                                     0, 0, 0, nullptr, nullptr, 1.f, 1);
        transp_b<<<dim3(8, 8, 16), 256, 0, stream>>>(QKV2 + 1024, Vt2, 512, 512, 1536,
                                                     (long)512 * 1536, 262144, 512);
        gemm_nt<<<dim3(4, 4, 16), 256, 0, stream>>>(QKV2, QKV2 + 512, Sg2, 512,
                                                    1536, 1536, 512,
                                                    (long)512 * 1536, (long)512 * 1536, 262144,
                                                    nullptr, nullptr,
                                                    0.04419417382415922f, 0);
        softmax_q<<<dim3(16, 8), 64, 0, stream>>>(Sg2, Pg2);
        gemm_nt<<<dim3(4, 4, 16), 256, 0, stream>>>(Vt2, Pg2, zT2, 512, 512, 512, 512,
                                                    262144, 262144, 262144, nullptr, nullptr,
                                                    1.f, 1);
        transp_b<<<dim3(8, 8, 16), 256, 0, stream>>>(zT2, zp + (long)G * 16 * 512,
                                                     512, 512, 512, 262144, 512, 32768);
    }

    // phase 3: GRU — MFMA, 128 blocks (8 XCD-confined bg x 16 unit-slices)
    zero_kernel<<<256, 256, 0, stream>>>((float*)hx, 65536);
    for (int l = 0; l < 2; l++) {
        const u16* Aseq = (l == 0) ? zp : h1bf;
        u16* seqOut = (l == 0) ? h1bf : h2bf;
        const u16* WiL = WiB + (long)l * 1536 * 512;
        const u16* WhL = WhB + (long)l * 1536 * 512;
        const float* biL = bi + (long)l * 1536;
        const float* bhL = bh + (long)l * 1536;
        for (int seg = 0; seg < 4; seg++) {
            gemm_nt<<<dim3(12, 64, 1), 256, 0, stream>>>(
                Aseq + (long)seg * 128 * 64 * 512, WiL, gi, 512, 512, 512, 1536,
                0, 0, 0, biL, nullptr, 1.f, 0);
            const float* giP = gi;
            u16* soP = seqOut;
            int s0v = seg * 128;
            int lv = l;
            void* args[] = { (void*)&giP, (void*)&WhL, (void*)&bhL, (void*)&soP,
                             (void*)&hx, (void*)&s0v, (void*)&lv };
            hipLaunchCooperativeKernel((void*)gru_mfma, dim3(128), dim3(256),
                                       args, 0, stream);
        }
    }

    final_kernel<<<8192, 256, 0, stream>>>(h2bf, Wf, bfin, out);
}